// Round 5
// baseline (387.840 us; speedup 1.0000x reference)
//
#include <hip/hip_runtime.h>
#include <cstddef>

// Problem constants
static constexpr int kB    = 256;   // batch
static constexpr int kS    = 196;   // att size (sequence)
static constexpr int kRNN  = 1024;  // rnn size
static constexpr int kATTH = 512;   // att hidden size
static constexpr int kQ    = 7;     // s-chunks per batch element
static constexpr int kSC   = 28;    // 28 s per chunk (7*28 = 196)

// Workspace layout (floats):
//   att_h : kB*kATTH   = 131072  (512 KB)
//   esum  : kB*kQ      =   1792
//   part  : kB*kQ*kRNN = 1835008 (7.3 MB)
static constexpr size_t kOffAttH = 0;
static constexpr size_t kOffEsum = kOffAttH + (size_t)kB * kATTH;
static constexpr size_t kOffPart = 133120;  // 16B-aligned past esum

__device__ __forceinline__ float fast_tanh(float x) {
    x = fminf(12.0f, fmaxf(-12.0f, x));
    float e = __expf(2.0f * x);
    return __fdividef(e - 1.0f, e + 1.0f);
}

__device__ __forceinline__ float dot8t(const float4 p0, const float4 p1,
                                       const float4 ah0, const float4 ah1,
                                       const float4 wa0, const float4 wa1) {
    float r;
    r  = fast_tanh(p0.x + ah0.x) * wa0.x;
    r += fast_tanh(p0.y + ah0.y) * wa0.y;
    r += fast_tanh(p0.z + ah0.z) * wa0.z;
    r += fast_tanh(p0.w + ah0.w) * wa0.w;
    r += fast_tanh(p1.x + ah1.x) * wa1.x;
    r += fast_tanh(p1.y + ah1.y) * wa1.y;
    r += fast_tanh(p1.z + ah1.z) * wa1.z;
    r += fast_tanh(p1.w + ah1.w) * wa1.w;
    return r;
}

// ---- K1: att_h[b,:] = W h_b + bias. Grid kB*4, 256 threads.
// Block (b, rq) computes atth rows rq*128 .. rq*128+127; wave w does 32 rows.
__global__ __launch_bounds__(256, 4) void k1_atth(
    const float* __restrict__ h, const float* __restrict__ w_h2att,
    const float* __restrict__ b_h2att, float* __restrict__ att_h) {
    const int b  = blockIdx.x >> 2;
    const int rq = blockIdx.x & 3;
    const int tid = threadIdx.x;
    const int lane = tid & 63;
    const int wave = tid >> 6;  // 0..3

    const float* hb = &h[(size_t)b * kRNN];
    const int k0 = lane << 2;  // lane covers k0, k0+256, k0+512, k0+768
    const float4 h0 = *(const float4*)&hb[k0];
    const float4 h1 = *(const float4*)&hb[k0 + 256];
    const float4 h2 = *(const float4*)&hb[k0 + 512];
    const float4 h3 = *(const float4*)&hb[k0 + 768];
    const int abase = rq * 128 + wave * 32;
#pragma unroll 2
    for (int r = 0; r < 32; ++r) {
        const int a = abase + r;
        const float* wr = &w_h2att[(size_t)a * kRNN + k0];
        const float4 x0 = *(const float4*)(wr);
        const float4 x1 = *(const float4*)(wr + 256);
        const float4 x2 = *(const float4*)(wr + 512);
        const float4 x3 = *(const float4*)(wr + 768);
        float d;
        d  = x0.x * h0.x + x0.y * h0.y + x0.z * h0.z + x0.w * h0.w;
        d += x1.x * h1.x + x1.y * h1.y + x1.z * h1.z + x1.w * h1.w;
        d += x2.x * h2.x + x2.y * h2.y + x2.z * h2.z + x2.w * h2.w;
        d += x3.x * h3.x + x3.y * h3.y + x3.z * h3.z + x3.w * h3.w;
#pragma unroll
        for (int off = 32; off > 0; off >>= 1) d += __shfl_xor(d, off, 64);
        if (lane == 0) att_h[(size_t)b * kATTH + a] = d + b_h2att[a];
    }
}

// ---- K23: fused scores + partial weighted sum for chunk (b,q), 28 rows.
// All loads are unconditional batches with compile-time indices: nothing
// for the compiler to sink. 1792 blocks (7/CU), target 24 waves/CU.
__global__ __launch_bounds__(256, 6) void k23_score_pv(
    const float* __restrict__ att_feats, const float* __restrict__ p_att,
    const float* __restrict__ att_h, const float* __restrict__ w_alpha,
    const float* __restrict__ b_alpha, float* __restrict__ esum,
    float* __restrict__ part) {
    const int q = blockIdx.x;  // 0..6
    const int b = blockIdx.y;  // 0..255
    const int tid = threadIdx.x;
    const int lane = tid & 63;
    const int wave = tid >> 6;  // 0..3

    __shared__ float sE[kSC];
    __shared__ float sEw[4];

    // ---- Phase A: 28 score rows; wave w owns rows {w, w+4, ..., w+24}.
    const int col = lane << 3;  // 8 atth elements per lane (64*8 = 512)
    const float4 ah0 = *(const float4*)&att_h[(size_t)b * kATTH + col];
    const float4 ah1 = *(const float4*)&att_h[(size_t)b * kATTH + col + 4];
    const float4 wa0 = *(const float4*)&w_alpha[col];
    const float4 wa1 = *(const float4*)&w_alpha[col + 4];
    const float balpha = b_alpha[0];

    // Data-independent bound: |score| <= sum|w_alpha| + |b_alpha| (|tanh|<=1)
    float sw = fabsf(wa0.x) + fabsf(wa0.y) + fabsf(wa0.z) + fabsf(wa0.w) +
               fabsf(wa1.x) + fabsf(wa1.y) + fabsf(wa1.z) + fabsf(wa1.w);
#pragma unroll
    for (int off = 32; off > 0; off >>= 1) sw += __shfl_xor(sw, off, 64);
    const float ebias = balpha - (sw + fabsf(balpha));  // score + ebias <= 0

    const float* pb = &p_att[((size_t)b * kS + (size_t)q * kSC) * kATTH + col];
    float esumw = 0.f;

    {   // Batch 1: rows w, w+4, w+8, w+12 — 8 unconditional loads.
        float4 pa[8];
#pragma unroll
        for (int j = 0; j < 4; ++j) {
            const float* p = pb + (size_t)(wave + 4 * j) * kATTH;
            pa[2 * j]     = *(const float4*)p;
            pa[2 * j + 1] = *(const float4*)(p + 4);
        }
        float rr[4];
#pragma unroll
        for (int j = 0; j < 4; ++j)
            rr[j] = dot8t(pa[2 * j], pa[2 * j + 1], ah0, ah1, wa0, wa1);
#pragma unroll
        for (int off = 32; off > 0; off >>= 1) {
#pragma unroll
            for (int j = 0; j < 4; ++j) rr[j] += __shfl_xor(rr[j], off, 64);
        }
        if (lane == 0) {
#pragma unroll
            for (int j = 0; j < 4; ++j) {
                const float e = __expf(rr[j] + ebias);
                sE[wave + 4 * j] = e;
                esumw += e;
            }
        }
    }
    {   // Batch 2: rows w+16, w+20, w+24 — 6 unconditional loads.
        float4 pa[6];
#pragma unroll
        for (int j = 0; j < 3; ++j) {
            const float* p = pb + (size_t)(wave + 16 + 4 * j) * kATTH;
            pa[2 * j]     = *(const float4*)p;
            pa[2 * j + 1] = *(const float4*)(p + 4);
        }
        float rr[3];
#pragma unroll
        for (int j = 0; j < 3; ++j)
            rr[j] = dot8t(pa[2 * j], pa[2 * j + 1], ah0, ah1, wa0, wa1);
#pragma unroll
        for (int off = 32; off > 0; off >>= 1) {
#pragma unroll
            for (int j = 0; j < 3; ++j) rr[j] += __shfl_xor(rr[j], off, 64);
        }
        if (lane == 0) {
#pragma unroll
            for (int j = 0; j < 3; ++j) {
                const float e = __expf(rr[j] + ebias);
                sE[wave + 16 + 4 * j] = e;
                esumw += e;
            }
        }
    }
    if (lane == 0) sEw[wave] = esumw;
    __syncthreads();
    if (tid == 0) esum[b * kQ + q] = sEw[0] + sEw[1] + sEw[2] + sEw[3];

    // ---- Phase C: thread owns float4 d-slot tid; 4 batches of 7 rows.
    const float* af =
        &att_feats[((size_t)b * kS + (size_t)q * kSC) * kRNN + (tid << 2)];
    float4 acc = {0.f, 0.f, 0.f, 0.f};
#pragma unroll
    for (int o = 0; o < 4; ++o) {
        float4 v[7];
#pragma unroll
        for (int j = 0; j < 7; ++j)
            v[j] = *(const float4*)(af + (size_t)(o * 7 + j) * kRNN);
#pragma unroll
        for (int j = 0; j < 7; ++j) {
            const float w = sE[o * 7 + j];
            acc.x += w * v[j].x; acc.y += w * v[j].y;
            acc.z += w * v[j].z; acc.w += w * v[j].w;
        }
    }
    *(float4*)&part[((size_t)(b * kQ + q)) * kRNN + (tid << 2)] = acc;
}

// ---- K4: out[b,:] = (sum_q part[b][q][:]) / (sum_q esum[b][q])
__global__ __launch_bounds__(256) void k4_combine(
    const float* __restrict__ part, const float* __restrict__ esum,
    float* __restrict__ out) {
    const int b = blockIdx.x;
    const int tid = threadIdx.x;

    const float* es = &esum[b * kQ];
    float tot = 0.f;
#pragma unroll
    for (int j = 0; j < kQ; ++j) tot += es[j];
    const float inv = __fdividef(1.0f, tot);

    const float* pb = &part[(size_t)b * kQ * kRNN + (tid << 2)];
    float4 a[kQ];
#pragma unroll
    for (int j = 0; j < kQ; ++j)
        a[j] = *(const float4*)(pb + (size_t)j * kRNN);
    float4 o = {0.f, 0.f, 0.f, 0.f};
#pragma unroll
    for (int j = 0; j < kQ; ++j) {
        o.x += a[j].x; o.y += a[j].y; o.z += a[j].z; o.w += a[j].w;
    }
    o.x *= inv; o.y *= inv; o.z *= inv; o.w *= inv;
    *(float4*)&out[(size_t)b * kRNN + (tid << 2)] = o;
}

extern "C" void kernel_launch(void* const* d_in, const int* in_sizes, int n_in,
                              void* d_out, int out_size, void* d_ws, size_t ws_size,
                              hipStream_t stream) {
    const float* h         = (const float*)d_in[0];
    const float* att_feats = (const float*)d_in[1];
    const float* p_att     = (const float*)d_in[2];
    const float* w_h2att   = (const float*)d_in[3];
    const float* b_h2att   = (const float*)d_in[4];
    const float* w_alpha   = (const float*)d_in[5];
    const float* b_alpha   = (const float*)d_in[6];
    float* out = (float*)d_out;

    float* ws    = (float*)d_ws;
    float* att_h = ws + kOffAttH;
    float* esum  = ws + kOffEsum;
    float* part  = ws + kOffPart;

    k1_atth<<<kB * 4, 256, 0, stream>>>(h, w_h2att, b_h2att, att_h);
    k23_score_pv<<<dim3(kQ, kB), 256, 0, stream>>>(att_feats, p_att, att_h,
                                                   w_alpha, b_alpha, esum, part);
    k4_combine<<<kB, 256, 0, stream>>>(part, esum, out);
}